// Round 9
// baseline (52.253 us; speedup 1.0000x reference)
//
#include <hip/hip_runtime.h>
#include <hip/hip_bf16.h>

#define BB   8
#define CC   128
#define TLEN 8192
#define TT   64                      // t per sub-tile
#define TBLK 128                     // t per block = 2 pipelined sub-tiles
#define NB   (BB * (TLEN / TBLK))    // 512 blocks = 2/CU

typedef __attribute__((ext_vector_type(8))) short short8;
typedef __attribute__((ext_vector_type(4))) float f32x4;

__device__ __forceinline__ short f2bf(float f) {
    union { float f; unsigned u; } v; v.f = f;
    return (short)((v.u + 0x7FFFu + ((v.u >> 16) & 1u)) >> 16);
}
__device__ __forceinline__ float bf2f(unsigned short h) {
    union { unsigned u; float f; } v; v.u = ((unsigned)h) << 16;
    return v.f;
}
// Row swizzle on c-octets: bijective per t-row, preserves 16B frag alignment.
__device__ __forceinline__ int swz(int t, int c) {
    return c ^ (((t ^ (t >> 3)) & 15) << 3);
}
// Raw workgroup barrier: waits LDS ops only — does NOT drain vmcnt,
// so global loads issued before it stay in flight (unlike __syncthreads).
__device__ __forceinline__ void barrier_lds() {
    asm volatile("s_waitcnt lgkmcnt(0)" ::: "memory");
    __builtin_amdgcn_s_barrier();
    asm volatile("" ::: "memory");
}

__device__ __forceinline__ void compute_tile(
    const short (*xb)[CC], const short (*zb)[CC], const short8 (&af)[4],
    int wid, int r15, int q4, int tbase, int b, int pl, int xl,
    float cx, float cz, float oms, const float* __restrict__ blin,
    float* __restrict__ out, float& lsum)
{
    f32x4 aX[4], aZ[4];   // D layout: col(t)=lane&15, row(d)=q4*4+reg
    #pragma unroll
    for (int tt = 0; tt < 4; ++tt) { aX[tt] = (f32x4){0,0,0,0}; aZ[tt] = (f32x4){0,0,0,0}; }

    #pragma unroll
    for (int ks = 0; ks < 4; ++ks) {
        #pragma unroll
        for (int tt = 0; tt < 4; ++tt) {
            const int tr = tt * 16 + r15;
            const int cs = swz(tr, ks * 32 + q4 * 8);
            const short8 xa = *reinterpret_cast<const short8*>(&xb[tr][cs]);
            const short8 za = *reinterpret_cast<const short8*>(&zb[tr][cs]);
            aX[tt] = __builtin_amdgcn_mfma_f32_16x16x32_bf16(af[ks], xa, aX[tt], 0, 0, 0);
            aZ[tt] = __builtin_amdgcn_mfma_f32_16x16x32_bf16(af[ks], za, aZ[tt], 0, 0, 0);
        }
    }

    #pragma unroll
    for (int rr = 0; rr < 4; ++rr) {
        const int d  = wid * 16 + q4 * 4 + rr;
        const float bl = blin[d];
        float* orow = out + 1 + (size_t)(b * CC + d) * TLEN + tbase;
        #pragma unroll
        for (int tt = 0; tt < 4; ++tt) {
            const int tl = tt * 16 + r15;
            const int tg = tbase + tl;
            const float s  = cx * aX[tt][rr] + cz * aZ[tt][rr];
            const bool pm  = tg >= pl;
            const float ov = (pm ? s : 0.0f) + bl;
            const int cs   = swz(tl, d);
            const float w  = oms * bf2f((unsigned short)zb[tl][cs]);
            orow[tl] = ov + w;
            if (pm & (tg < xl)) {
                const float xf = bf2f((unsigned short)xb[tl][cs]);
                const float df = ov - (xf - w);
                lsum += df * df;
            }
        }
    }
}

__global__ __launch_bounds__(512, 4)   // 4 waves/EU = 16 waves/CU = 2 blocks/CU
void cfm_fused(const float* __restrict__ x1, const float* __restrict__ tsm,
               const float* __restrict__ z, const float* __restrict__ W,
               const float* __restrict__ blin, const int* __restrict__ xlens,
               const int* __restrict__ plens, float* __restrict__ out)
{
    __shared__ short xt[2][TT][CC];   // bf16 [t][c], swizzled, double-buffered
    __shared__ short zt[2][TT][CC];
    __shared__ float red[8];

    const int bi = blockIdx.x;
    const int b  = bi & 7;
    const int t0 = (bi >> 3) * TBLK;

    const int tid  = threadIdx.x;
    const int lane = tid & 63;
    const int wid  = tid >> 6;          // 0..7 = dtile
    const int r15  = lane & 15;
    const int q4   = lane >> 4;

    const float ts  = tsm[b];
    const int   pl  = plens[b];
    const int   xl  = xlens[b];
    const float oms = 0.999999f;        // 1 - sigma
    const float cz  = 1.0f - oms * ts;
    const float cx  = ts;

    // staging geometry: 16 lanes span 64 t (256B runs) per c-row
    const int tj = (tid & 15) * 4;
    const int cr = tid >> 4;            // 0..31
    const size_t gb0 = (size_t)b * CC * TLEN + (size_t)t0 + tj;

    // ---- issue tile-0 loads (8 float4, all up front) ----
    float4 xv0[4], zv0[4];
    #pragma unroll
    for (int p = 0; p < 4; ++p) {
        xv0[p] = *reinterpret_cast<const float4*>(x1 + gb0 + (size_t)(cr + p * 32) * TLEN);
        zv0[p] = *reinterpret_cast<const float4*>(z  + gb0 + (size_t)(cr + p * 32) * TLEN);
    }

    // ---- W fragments (L2/L3-hot), converted under the load shadow ----
    short8 af[4];
    {
        const int row = wid * 16 + r15;
        #pragma unroll
        for (int ks = 0; ks < 4; ++ks) {
            const float4 w0 = *reinterpret_cast<const float4*>(W + row * CC + ks * 32 + q4 * 8);
            const float4 w1 = *reinterpret_cast<const float4*>(W + row * CC + ks * 32 + q4 * 8 + 4);
            short8 a;
            a[0] = f2bf(w0.x); a[1] = f2bf(w0.y); a[2] = f2bf(w0.z); a[3] = f2bf(w0.w);
            a[4] = f2bf(w1.x); a[5] = f2bf(w1.y); a[6] = f2bf(w1.z); a[7] = f2bf(w1.w);
            af[ks] = a;
        }
    }

    // ---- stage tile 0 -> buf 0 ----
    #pragma unroll
    for (int p = 0; p < 4; ++p) {
        const int c = cr + p * 32;
        const float* xs = reinterpret_cast<const float*>(&xv0[p]);
        const float* zs = reinterpret_cast<const float*>(&zv0[p]);
        #pragma unroll
        for (int j = 0; j < 4; ++j) {
            const int t  = tj + j;
            const int cs = swz(t, c);
            xt[0][t][cs] = f2bf(xs[j]);
            zt[0][t][cs] = f2bf(zs[j]);
        }
    }

    // ---- issue tile-1 loads BEFORE the barrier; raw barrier keeps them in flight ----
    float4 xv1[4], zv1[4];
    #pragma unroll
    for (int p = 0; p < 4; ++p) {
        xv1[p] = *reinterpret_cast<const float4*>(x1 + gb0 + TT + (size_t)(cr + p * 32) * TLEN);
        zv1[p] = *reinterpret_cast<const float4*>(z  + gb0 + TT + (size_t)(cr + p * 32) * TLEN);
    }

    barrier_lds();   // buf0 visible; tile-1 loads still in flight

    float lsum = 0.0f;
    compute_tile(xt[0], zt[0], af, wid, r15, q4, t0, b, pl, xl, cx, cz, oms, blin, out, lsum);

    // ---- stage tile 1 -> buf 1 (vmcnt waited here, at first use) ----
    #pragma unroll
    for (int p = 0; p < 4; ++p) {
        const int c = cr + p * 32;
        const float* xs = reinterpret_cast<const float*>(&xv1[p]);
        const float* zs = reinterpret_cast<const float*>(&zv1[p]);
        #pragma unroll
        for (int j = 0; j < 4; ++j) {
            const int t  = tj + j;
            const int cs = swz(t, c);
            xt[1][t][cs] = f2bf(xs[j]);
            zt[1][t][cs] = f2bf(zs[j]);
        }
    }

    barrier_lds();   // buf1 visible

    compute_tile(xt[1], zt[1], af, wid, r15, q4, t0 + TT, b, pl, xl, cx, cz, oms, blin, out, lsum);

    // ---- loss: wave reduce -> block reduce -> one atomicAdd ----
    #pragma unroll
    for (int off = 32; off >= 1; off >>= 1) lsum += __shfl_down(lsum, off);
    if (lane == 0) red[wid] = lsum;
    barrier_lds();
    if (tid == 0) {
        float s = 0.0f;
        #pragma unroll
        for (int w = 0; w < 8; ++w) s += red[w];
        atomicAdd(out, s / (1024.0f * (float)(xl - pl)));   // 1/(B*C*(xl-pl))
    }
}

extern "C" void kernel_launch(void* const* d_in, const int* in_sizes, int n_in,
                              void* d_out, int out_size, void* d_ws, size_t ws_size,
                              hipStream_t stream) {
    const float* x1    = (const float*)d_in[0];
    // d_in[1] = mu (unused), d_in[2] = style (unused)
    const float* tsm   = (const float*)d_in[3];
    const float* z     = (const float*)d_in[4];
    const float* W     = (const float*)d_in[5];
    const float* blin  = (const float*)d_in[6];
    const int*   xlens = (const int*)d_in[7];
    const int*   plens = (const int*)d_in[8];
    float* out = (float*)d_out;

    hipMemsetAsync(out, 0, sizeof(float), stream);   // zero the loss slot
    cfm_fused<<<NB, 512, 0, stream>>>(x1, tsm, z, W, blin, xlens, plens, out);
}

// Round 10
// 32.399 us; speedup vs baseline: 1.6128x; 1.6128x over previous
//
#include <hip/hip_runtime.h>
#include <hip/hip_bf16.h>

#define BB   8
#define CC   128
#define TLEN 8192
#define TBLK 128                     // t per block, single monolithic tile
#define NB   (BB * (TLEN / TBLK))    // 512 blocks = 2/CU

typedef __attribute__((ext_vector_type(8))) short short8;
typedef __attribute__((ext_vector_type(4))) float f32x4;

__device__ __forceinline__ short f2bf(float f) {
    union { float f; unsigned u; } v; v.f = f;
    return (short)((v.u + 0x7FFFu + ((v.u >> 16) & 1u)) >> 16);
}
__device__ __forceinline__ float bf2f(unsigned short h) {
    union { unsigned u; float f; } v; v.u = ((unsigned)h) << 16;
    return v.f;
}
// Row swizzle on c-octets: bijective per t-row, preserves 16B frag alignment.
__device__ __forceinline__ int swz(int t, int c) {
    return c ^ (((t ^ (t >> 3)) & 15) << 3);
}

__global__ __launch_bounds__(512, 4)   // 4 waves/EU = 2 blocks/CU
void cfm_fused(const float* __restrict__ x1, const float* __restrict__ tsm,
               const float* __restrict__ z, const float* __restrict__ W,
               const float* __restrict__ blin, const int* __restrict__ xlens,
               const int* __restrict__ plens, float* __restrict__ out)
{
    __shared__ short xt[TBLK][CC];   // bf16 [t][c], swizzled rows
    __shared__ short zt[TBLK][CC];
    __shared__ float red[8];

    const int bi = blockIdx.x;
    const int b  = bi & 7;           // XCD x serves batch x: 4MB x + 4MB z per L2
    const int t0 = (bi >> 3) * TBLK;

    const int tid  = threadIdx.x;
    const int lane = tid & 63;
    const int wid  = tid >> 6;          // 0..7 = dtile
    const int r15  = lane & 15;
    const int q4   = lane >> 4;

    const float ts  = tsm[b];
    const int   pl  = plens[b];
    const int   xl  = xlens[b];
    const float oms = 0.999999f;        // 1 - sigma
    const float cz  = 1.0f - oms * ts;
    const float cx  = ts;

    // ---- issue ALL 16 global float4 loads up front (512B/row spans) ----
    const int tpart = (tid & 31) * 4;   // local t base
    const int c0    = tid >> 5;         // 0..15
    const size_t rowb = (size_t)b * CC * TLEN + (size_t)t0 + tpart;

    float4 xv[8], zv[8];
    #pragma unroll
    for (int p = 0; p < 8; ++p)
        xv[p] = *reinterpret_cast<const float4*>(x1 + rowb + (size_t)(c0 + p * 16) * TLEN);
    #pragma unroll
    for (int p = 0; p < 8; ++p)
        zv[p] = *reinterpret_cast<const float4*>(z + rowb + (size_t)(c0 + p * 16) * TLEN);

    // ---- W fragments for this wave's dtile (L2-hot), cvt under load shadow ----
    short8 af[4];
    {
        const int row = wid * 16 + r15;
        #pragma unroll
        for (int ks = 0; ks < 4; ++ks) {
            const float4 w0 = *reinterpret_cast<const float4*>(W + row * CC + ks * 32 + q4 * 8);
            const float4 w1 = *reinterpret_cast<const float4*>(W + row * CC + ks * 32 + q4 * 8 + 4);
            short8 a;
            a[0] = f2bf(w0.x); a[1] = f2bf(w0.y); a[2] = f2bf(w0.z); a[3] = f2bf(w0.w);
            a[4] = f2bf(w1.x); a[5] = f2bf(w1.y); a[6] = f2bf(w1.z); a[7] = f2bf(w1.w);
            af[ks] = a;
        }
    }

    // ---- stage: transpose + cvt into swizzled bf16 tiles ----
    #pragma unroll
    for (int p = 0; p < 8; ++p) {
        const int c = c0 + p * 16;
        const float* xs = reinterpret_cast<const float*>(&xv[p]);
        const float* zs = reinterpret_cast<const float*>(&zv[p]);
        #pragma unroll
        for (int j = 0; j < 4; ++j) {
            const int t  = tpart + j;
            const int cs = swz(t, c);
            xt[t][cs] = f2bf(xs[j]);
            zt[t][cs] = f2bf(zs[j]);
        }
    }
    __syncthreads();

    // ---- MFMA: out tile [128 d][128 t]; wave w owns d in [16w, 16w+16) ----
    f32x4 aX[8], aZ[8];
    #pragma unroll
    for (int tt = 0; tt < 8; ++tt) { aX[tt] = (f32x4){0,0,0,0}; aZ[tt] = (f32x4){0,0,0,0}; }

    #pragma unroll
    for (int ks = 0; ks < 4; ++ks) {
        #pragma unroll
        for (int tt = 0; tt < 8; ++tt) {
            const int tr = tt * 16 + r15;
            const int cs = swz(tr, ks * 32 + q4 * 8);
            const short8 xa = *reinterpret_cast<const short8*>(&xt[tr][cs]);
            const short8 za = *reinterpret_cast<const short8*>(&zt[tr][cs]);
            aX[tt] = __builtin_amdgcn_mfma_f32_16x16x32_bf16(af[ks], xa, aX[tt], 0, 0, 0);
            aZ[tt] = __builtin_amdgcn_mfma_f32_16x16x32_bf16(af[ks], za, aZ[tt], 0, 0, 0);
        }
    }

    // ---- epilogue: D layout col(t)=lane&15, row(d)=q4*4+reg ----
    float lsum = 0.0f;
    #pragma unroll
    for (int rr = 0; rr < 4; ++rr) {
        const int d  = wid * 16 + q4 * 4 + rr;
        const float bl = blin[d];
        float* orow = out + 1 + (size_t)(b * CC + d) * TLEN + t0;
        #pragma unroll
        for (int tt = 0; tt < 8; ++tt) {
            const int tl = tt * 16 + r15;
            const int tg = t0 + tl;
            const float s  = cx * aX[tt][rr] + cz * aZ[tt][rr];
            const bool pm  = tg >= pl;
            const float ov = (pm ? s : 0.0f) + bl;
            const int cs   = swz(tl, d);
            const float w  = oms * bf2f((unsigned short)zt[tl][cs]);
            orow[tl] = ov + w;
            if (pm & (tg < xl)) {
                const float xf = bf2f((unsigned short)xt[tl][cs]);
                const float df = ov - (xf - w);
                lsum += df * df;
            }
        }
    }

    // ---- loss: wave reduce -> block reduce -> one atomicAdd ----
    #pragma unroll
    for (int off = 32; off >= 1; off >>= 1) lsum += __shfl_down(lsum, off);
    if (lane == 0) red[wid] = lsum;
    __syncthreads();
    if (tid == 0) {
        float s = 0.0f;
        #pragma unroll
        for (int w = 0; w < 8; ++w) s += red[w];
        atomicAdd(out, s / (1024.0f * (float)(xl - pl)));   // 1/(B*C*(xl-pl))
    }
}

extern "C" void kernel_launch(void* const* d_in, const int* in_sizes, int n_in,
                              void* d_out, int out_size, void* d_ws, size_t ws_size,
                              hipStream_t stream) {
    const float* x1    = (const float*)d_in[0];
    // d_in[1] = mu (unused), d_in[2] = style (unused)
    const float* tsm   = (const float*)d_in[3];
    const float* z     = (const float*)d_in[4];
    const float* W     = (const float*)d_in[5];
    const float* blin  = (const float*)d_in[6];
    const int*   xlens = (const int*)d_in[7];
    const int*   plens = (const int*)d_in[8];
    float* out = (float*)d_out;

    hipMemsetAsync(out, 0, sizeof(float), stream);   // zero the loss slot
    cfm_fused<<<NB, 512, 0, stream>>>(x1, tsm, z, W, blin, xlens, plens, out);
}